// Round 4
// baseline (49.802 us; speedup 1.0000x reference)
//
#include <hip/hip_runtime.h>

#define NN 8192
#define MARGIN_F 1.0f
#define BLOCK 256
#define JPT 2                       // j's per thread (share one LDS read)
#define ITILE 64                    // i-tile = one wave: ballot compaction
#define GX (NN / (BLOCK * JPT))     // 16
#define GY (NN / ITILE)             // 128
#define NBLK (GX * GY)              // 2048

// Single fused kernel: per-block partials -> device-scope publish ->
// last-arriving block (ticket) reduces all partials and writes the output.
__global__ __launch_bounds__(BLOCK) void rl_fused(const float* __restrict__ preds,
                                                  const float* __restrict__ targets,
                                                  unsigned* __restrict__ ticket,
                                                  unsigned* __restrict__ psum_bits,
                                                  unsigned* __restrict__ pcnt,
                                                  float* __restrict__ out) {
    __shared__ float2   si[ITILE];   // {MARGIN - p_i, d_i}, event rows only
    __shared__ unsigned s_cnt;
    __shared__ int      s_last;

    const int tid = threadIdx.x;

    // --- single-wave stage + ballot-compact of the i-tile
    if (tid < 64) {
        const int   gi = blockIdx.y * ITILE + tid;
        const float d  = targets[2 * gi];
        const float e  = targets[2 * gi + 1];
        const bool  ev = (e == 1.0f);
        const unsigned long long bal = __ballot(ev);
        const int pre = __popcll(bal & ((1ull << tid) - 1ull));
        if (ev) si[pre] = make_float2(MARGIN_F - preds[gi], d);
        if (tid == 0) s_cnt = (unsigned)__popcll(bal);
    }
    __syncthreads();

    const unsigned m   = s_cnt;
    const int      j1  = blockIdx.x * (BLOCK * JPT) + tid;
    const int      j2  = j1 + BLOCK;
    const float    pj1 = preds[j1],        pj2 = preds[j2];
    const float    dj1 = targets[2 * j1],  dj2 = targets[2 * j2];

    float    f1 = 0.f, f2 = 0.f;
    unsigned c1 = 0u,  c2 = 0u;

    #pragma unroll 4
    for (unsigned k = 0; k < m; ++k) {
        const float2 a  = si[k];
        const bool   b1 = a.y < dj1;
        const bool   b2 = a.y < dj2;
        f1 += b1 ? fmaxf(a.x + pj1, 0.f) : 0.f;
        f2 += b2 ? fmaxf(a.x + pj2, 0.f) : 0.f;
        c1 += b1;
        c2 += b2;
    }
    float    fsum = f1 + f2;
    unsigned cnt  = c1 + c2;

    // --- block reduce
    #pragma unroll
    for (int off = 32; off > 0; off >>= 1) {
        fsum += __shfl_down(fsum, off);
        cnt  += __shfl_down(cnt,  off);
    }
    __shared__ float    wsum[BLOCK / 64];
    __shared__ unsigned wcnt[BLOCK / 64];
    const int wave = tid >> 6;
    const int lane = tid & 63;
    if (lane == 0) { wsum[wave] = fsum; wcnt[wave] = cnt; }
    __syncthreads();

    if (tid == 0) {
        float    s = 0.f;
        unsigned c = 0u;
        #pragma unroll
        for (int w = 0; w < BLOCK / 64; ++w) { s += wsum[w]; c += wcnt[w]; }
        const int bid = blockIdx.y * gridDim.x + blockIdx.x;
        atomicExch(&psum_bits[bid], __float_as_uint(s));   // device-scope publish
        atomicExch(&pcnt[bid], c);
        __threadfence();                                   // release
        const unsigned old = atomicAdd(ticket, 1u);        // ticket
        s_last = (old == NBLK - 1u);
    }
    __syncthreads();

    // --- last-arriving block: reduce all 2048 partials, write output
    if (s_last) {
        __threadfence();                                   // acquire
        double             S = 0.0;
        unsigned long long C = 0ull;
        #pragma unroll
        for (int w = 0; w < NBLK / BLOCK; ++w) {
            const int idx = w * BLOCK + tid;
            S += (double)__uint_as_float(atomicAdd(&psum_bits[idx], 0u));
            C += (unsigned long long)atomicAdd(&pcnt[idx], 0u);
        }
        #pragma unroll
        for (int off = 32; off > 0; off >>= 1) {
            S += __shfl_down(S, off);
            C += __shfl_down(C, off);
        }
        __shared__ double             ds2[BLOCK / 64];
        __shared__ unsigned long long cs2[BLOCK / 64];
        if (lane == 0) { ds2[wave] = S; cs2[wave] = C; }
        __syncthreads();
        if (tid == 0) {
            double             SS = 0.0;
            unsigned long long CC = 0ull;
            #pragma unroll
            for (int w = 0; w < BLOCK / 64; ++w) { SS += ds2[w]; CC += cs2[w]; }
            out[0] = (CC > 0ull) ? (float)(SS / (double)CC) : 0.0f;
        }
    }
}

extern "C" void kernel_launch(void* const* d_in, const int* in_sizes, int n_in,
                              void* d_out, int out_size, void* d_ws, size_t ws_size,
                              hipStream_t stream) {
    const float* preds   = (const float*)d_in[0];
    const float* targets = (const float*)d_in[1];
    float*       out     = (float*)d_out;

    unsigned* ticket    = (unsigned*)d_ws;                         // 4 B
    unsigned* psum_bits = (unsigned*)((char*)d_ws + 64);           // NBLK * 4 B
    unsigned* pcnt      = (unsigned*)((char*)d_ws + 64 + NBLK * 4);

    // ticket must be 0 at kernel entry every call (ws is poisoned 0xAA once
    // and never re-poisoned; partials don't need init — written before read).
    hipMemsetAsync(ticket, 0, sizeof(unsigned), stream);

    dim3 grid(GX, GY);                  // (16, 128) = 2048 blocks
    rl_fused<<<grid, BLOCK, 0, stream>>>(preds, targets, ticket, psum_bits, pcnt, out);
}

// Round 5
// 13.761 us; speedup vs baseline: 3.6191x; 3.6191x over previous
//
#include <hip/hip_runtime.h>
#include <cfloat>

#define NN 8192
#define MARGIN_F 1.0f
#define BLOCK 256
#define JPT 2                       // j's per thread (share one LDS read)
#define ITILE 64                    // i-tile = one wave: ballot compaction
#define GX (NN / (BLOCK * JPT))     // 16
#define GY (NN / ITILE)             // 128
#define NBLK (GX * GY)              // 2048 partials

__global__ __launch_bounds__(BLOCK) void rl_main(const float* __restrict__ preds,
                                                 const float* __restrict__ targets,
                                                 float* __restrict__ psum,
                                                 unsigned* __restrict__ pcnt) {
    __shared__ float2   si[ITILE + 8];  // {MARGIN - p_i, d_i}; +8 neutral pad
    __shared__ unsigned s_cnt;

    const int tid = threadIdx.x;

    // --- single-wave stage + ballot-compact + neutral pad
    if (tid < 64) {
        const int   gi = blockIdx.y * ITILE + tid;
        const float d  = targets[2 * gi];
        const float e  = targets[2 * gi + 1];
        const bool  ev = (e == 1.0f);
        const unsigned long long bal = __ballot(ev);
        const int      pre = __popcll(bal & ((1ull << tid) - 1ull));
        const unsigned m   = (unsigned)__popcll(bal);
        if (ev) si[pre] = make_float2(MARGIN_F - preds[gi], d);
        if (tid < 8) si[m + tid] = make_float2(0.0f, FLT_MAX);  // never passes d<dj
        if (tid == 0) s_cnt = m;
    }
    __syncthreads();

    const unsigned m   = s_cnt;
    const int      j1  = blockIdx.x * (BLOCK * JPT) + tid;
    const int      j2  = j1 + BLOCK;
    const float    pj1 = preds[j1],        pj2 = preds[j2];
    const float    dj1 = targets[2 * j1],  dj2 = targets[2 * j2];

    float    f1 = 0.f, f2 = 0.f;
    unsigned c1 = 0u,  c2 = 0u;

    // fixed-step unroll-8 loop; pad entries are neutral (mask always false)
    for (unsigned k = 0; k < m; k += 8) {
        #pragma unroll
        for (int u = 0; u < 8; ++u) {
            const float2 a  = si[k + u];
            const bool   b1 = a.y < dj1;
            const bool   b2 = a.y < dj2;
            f1 += b1 ? fmaxf(a.x + pj1, 0.f) : 0.f;
            f2 += b2 ? fmaxf(a.x + pj2, 0.f) : 0.f;
            c1 += b1;
            c2 += b2;
        }
    }
    float    fsum = f1 + f2;
    unsigned cnt  = c1 + c2;

    // --- block reduce
    #pragma unroll
    for (int off = 32; off > 0; off >>= 1) {
        fsum += __shfl_down(fsum, off);
        cnt  += __shfl_down(cnt,  off);
    }
    __shared__ float    wsum[BLOCK / 64];
    __shared__ unsigned wcnt[BLOCK / 64];
    const int wave = tid >> 6;
    const int lane = tid & 63;
    if (lane == 0) { wsum[wave] = fsum; wcnt[wave] = cnt; }
    __syncthreads();

    if (tid == 0) {
        float    s = 0.f;
        unsigned c = 0u;
        #pragma unroll
        for (int w = 0; w < BLOCK / 64; ++w) { s += wsum[w]; c += wcnt[w]; }
        const int bid = blockIdx.y * gridDim.x + blockIdx.x;
        psum[bid] = s;          // pure overwrite: no zero-init needed
        pcnt[bid] = c;
    }
}

__global__ __launch_bounds__(512) void rl_fin(const float4* __restrict__ psum4,
                                              const uint4* __restrict__ pcnt4,
                                              float* __restrict__ out) {
    const int tid = threadIdx.x;              // 512 threads × 1 float4/uint4 each
    const float4 s4 = psum4[tid];             // 512 * 4 = 2048 partials
    const uint4  c4 = pcnt4[tid];

    double             s = (double)((s4.x + s4.y) + (s4.z + s4.w));
    unsigned long long c = (unsigned long long)(c4.x + c4.y + c4.z + c4.w);

    #pragma unroll
    for (int off = 32; off > 0; off >>= 1) {
        s += __shfl_down(s, off);
        c += __shfl_down(c, off);
    }
    __shared__ double             ds[8];
    __shared__ unsigned long long cs[8];
    const int wave = tid >> 6;
    const int lane = tid & 63;
    if (lane == 0) { ds[wave] = s; cs[wave] = c; }
    __syncthreads();

    if (tid == 0) {
        double             S = 0.0;
        unsigned long long C = 0ull;
        #pragma unroll
        for (int w = 0; w < 8; ++w) { S += ds[w]; C += cs[w]; }
        out[0] = (C > 0ull) ? (float)(S / (double)C) : 0.0f;
    }
}

extern "C" void kernel_launch(void* const* d_in, const int* in_sizes, int n_in,
                              void* d_out, int out_size, void* d_ws, size_t ws_size,
                              hipStream_t stream) {
    const float* preds   = (const float*)d_in[0];
    const float* targets = (const float*)d_in[1];
    float*       out     = (float*)d_out;

    float*    psum = (float*)d_ws;                                  // 2048 * 4 B
    unsigned* pcnt = (unsigned*)((char*)d_ws + NBLK * sizeof(float));

    dim3 grid(GX, GY);                  // (16, 128) = 2048 blocks
    rl_main<<<grid, BLOCK, 0, stream>>>(preds, targets, psum, pcnt);
    rl_fin<<<1, 512, 0, stream>>>((const float4*)psum, (const uint4*)pcnt, out);
}